// Round 1
// baseline (205.255 us; speedup 1.0000x reference)
//
#include <hip/hip_runtime.h>

#define CC 20480      // columns of X
#define PP 2048       // P
#define NROWS 2047    // P-1 rows reduced
#define SRR 10
#define HH 1024
#define NCHUNK 32     // row chunks for partial sums

// ---------------- phase 1: shifted column partial sums ----------------
// shifted[i][j] = X[i*10][(j - p[i]) mod C]; accumulate per column over a
// chunk of rows. Deterministic (no atomics).
__global__ __launch_bounds__(256) void colsum_k(const float* __restrict__ X,
                                                const int* __restrict__ p,
                                                float* __restrict__ psum,
                                                int* __restrict__ pcnt) {
    int j = blockIdx.x * 256 + threadIdx.x;     // column 0..20479
    int chunk = blockIdx.y;
    int r0 = chunk * 64;
    int r1 = r0 + 64; if (r1 > NROWS) r1 = NROWS;
    float s = 0.f; int cnt = 0;
    for (int i = r0; i < r1; ++i) {
        int shift = p[i];                        // uniform across block -> scalar
        int src = j - shift; if (src < 0) src += CC;
        float v = X[(size_t)i * (size_t)(SRR * CC) + src];
        if (v == v) { s += v; ++cnt; }           // NaN-safe (none expected)
    }
    psum[(size_t)chunk * CC + j] = s;
    pcnt[(size_t)chunk * CC + j] = cnt;
}

// ---------------- phase 2: reduce partials at columns 10k -> x[k] ------
// No NaNs in X => forward-fill is identity => x[k] = mean of column 10k.
__global__ __launch_bounds__(256) void xcalc_k(const float* __restrict__ psum,
                                               const int* __restrict__ pcnt,
                                               float* __restrict__ x) {
    int k = blockIdx.x * 256 + threadIdx.x;
    if (k >= PP) return;
    int col = k * SRR;
    float s = 0.f; int cnt = 0;
    for (int c2 = 0; c2 < NCHUNK; ++c2) {
        s += psum[(size_t)c2 * CC + col];
        cnt += pcnt[(size_t)c2 * CC + col];
    }
    x[k] = (cnt > 0) ? (s / (float)cnt) : __int_as_float(0x7fc00000);
}

// ---------------- layer 1: h = relu(x * W1 + b1), W1 is (1024,1) -------
__global__ __launch_bounds__(256) void layer1_k(const float* __restrict__ x,
                                                const float* __restrict__ W1,
                                                const float* __restrict__ b1,
                                                float* __restrict__ h) {
    int idx = blockIdx.x * 256 + threadIdx.x;    // k*1024 + o
    int k = idx >> 10, o = idx & 1023;
    float v = x[k] * W1[o] + b1[o];
    h[idx] = v > 0.f ? v : 0.f;
}

// ---------------- GEMM: C[m][n] = relu(sum_k A[m][k]*B[n][k] + bias[n]) -
// A: M x K row-major, B: N x K row-major (i.e. h @ W^T). 64x64 tile, BK=32,
// 4x4 micro-tile per thread, tiles stored K-major in LDS (stride 68 floats
// keeps float4 reads 16B-aligned and banks spread).
template<int RELU>
__global__ __launch_bounds__(256) void gemm_nt(const float* __restrict__ A,
                                               const float* __restrict__ B,
                                               const float* __restrict__ bias,
                                               float* __restrict__ Cout,
                                               int M, int N, int K) {
    __shared__ float As[32][68];
    __shared__ float Bs[32][68];
    int bm = blockIdx.x * 64, bn = blockIdx.y * 64;
    int t = threadIdx.x;
    int tx = t & 15, ty = t >> 4;     // 16x16 thread grid
    int lr = t >> 3;                  // 0..31 (load row)
    int lc = (t & 7) << 2;            // 0,4,..,28 (load k-col)
    float acc[4][4] = {};
    for (int k0 = 0; k0 < K; k0 += 32) {
        #pragma unroll
        for (int h2 = 0; h2 < 2; ++h2) {
            int row = lr + h2 * 32;
            float4 av = *(const float4*)&A[(size_t)(bm + row) * K + k0 + lc];
            As[lc + 0][row] = av.x; As[lc + 1][row] = av.y;
            As[lc + 2][row] = av.z; As[lc + 3][row] = av.w;
            float4 bv = *(const float4*)&B[(size_t)(bn + row) * K + k0 + lc];
            Bs[lc + 0][row] = bv.x; Bs[lc + 1][row] = bv.y;
            Bs[lc + 2][row] = bv.z; Bs[lc + 3][row] = bv.w;
        }
        __syncthreads();
        #pragma unroll
        for (int kk = 0; kk < 32; ++kk) {
            float4 a = *(const float4*)&As[kk][ty << 2];
            float4 b = *(const float4*)&Bs[kk][tx << 2];
            float av4[4] = {a.x, a.y, a.z, a.w};
            float bv4[4] = {b.x, b.y, b.z, b.w};
            #pragma unroll
            for (int i = 0; i < 4; ++i)
                #pragma unroll
                for (int j2 = 0; j2 < 4; ++j2)
                    acc[i][j2] += av4[i] * bv4[j2];
        }
        __syncthreads();
    }
    #pragma unroll
    for (int i = 0; i < 4; ++i) {
        int row = bm + (ty << 2) + i;
        #pragma unroll
        for (int j2 = 0; j2 < 4; ++j2) {
            int col = bn + (tx << 2) + j2;
            float v = acc[i][j2] + bias[col];
            if (RELU) v = v > 0.f ? v : 0.f;
            Cout[(size_t)row * N + col] = v;
        }
    }
}

// ---------------- layer 4: y[k] = dot(h[k], W4) + b4 -------------------
__global__ __launch_bounds__(256) void layer4_k(const float* __restrict__ h,
                                                const float* __restrict__ W4,
                                                const float* __restrict__ b4,
                                                float* __restrict__ y) {
    int wave = threadIdx.x >> 6;
    int lane = threadIdx.x & 63;
    int row = blockIdx.x * 4 + wave;
    const float* hr = h + (size_t)row * HH;
    float s = 0.f;
    #pragma unroll
    for (int i = 0; i < HH / 64; ++i) s += hr[lane + 64 * i] * W4[lane + 64 * i];
    #pragma unroll
    for (int off = 32; off; off >>= 1) s += __shfl_down(s, off, 64);
    if (lane == 0) y[row] = s + b4[0];
}

extern "C" void kernel_launch(void* const* d_in, const int* in_sizes, int n_in,
                              void* d_out, int out_size, void* d_ws, size_t ws_size,
                              hipStream_t stream) {
    const float* X  = (const float*)d_in[0];
    const int*   p  = (const int*)d_in[1];
    const float* W1 = (const float*)d_in[2];
    const float* b1 = (const float*)d_in[3];
    const float* W2 = (const float*)d_in[4];
    const float* b2 = (const float*)d_in[5];
    const float* W3 = (const float*)d_in[6];
    const float* b3 = (const float*)d_in[7];
    const float* W4 = (const float*)d_in[8];
    const float* b4 = (const float*)d_in[9];
    float* out = (float*)d_out;

    char* ws = (char*)d_ws;
    size_t off = 0;
    float* psum = (float*)(ws + off); off += (size_t)NCHUNK * CC * 4;          // 2.62 MB
    int*   pcnt = (int*)  (ws + off); off += (size_t)NCHUNK * CC * 4;          // 2.62 MB
    float* xbuf = (float*)(ws + off); off += 4096 * 4;                         // pad
    float* h1   = (float*)(ws + off); off += (size_t)PP * HH * 4;              // 8.4 MB
    float* h2   = (float*)(ws + off); off += (size_t)PP * HH * 4;              // 8.4 MB

    colsum_k<<<dim3(80, NCHUNK), 256, 0, stream>>>(X, p, psum, pcnt);
    xcalc_k<<<8, 256, 0, stream>>>(psum, pcnt, xbuf);
    layer1_k<<<(PP * HH) / 256, 256, 0, stream>>>(xbuf, W1, b1, h1);
    gemm_nt<1><<<dim3(2048 / 64, 1024 / 64), 256, 0, stream>>>(h1, W2, b2, h2, 2048, 1024, 1024);
    gemm_nt<1><<<dim3(2048 / 64, 1024 / 64), 256, 0, stream>>>(h2, W3, b3, h1, 2048, 1024, 1024);
    layer4_k<<<PP / 4, 256, 0, stream>>>(h1, W4, b4, out);
}

// Round 2
// 155.796 us; speedup vs baseline: 1.3175x; 1.3175x over previous
//
#include <hip/hip_runtime.h>
#include <hip/hip_bf16.h>

#define CC 20480      // columns of X
#define PP 2048       // P
#define NROWS 2047    // rows reduced
#define SRR 10
#define HH 1024
#define NCHUNK 32

typedef __attribute__((ext_vector_type(8))) short short8;
typedef __attribute__((ext_vector_type(4))) float f32x4;

// ---------------- phase 1: shifted column partial sums ----------------
__global__ __launch_bounds__(256) void colsum_k(const float* __restrict__ X,
                                                const int* __restrict__ p,
                                                float* __restrict__ psum) {
    int j = blockIdx.x * 256 + threadIdx.x;
    int chunk = blockIdx.y;
    int r0 = chunk * 64;
    int r1 = r0 + 64; if (r1 > NROWS) r1 = NROWS;
    float s = 0.f;
    for (int i = r0; i < r1; ++i) {
        int src = j - p[i]; if (src < 0) src += CC;
        s += X[(size_t)i * (size_t)(SRR * CC) + src];
    }
    psum[(size_t)chunk * CC + j] = s;
}

// ---------------- phase 2: x[k] = mean of column 10k ------------------
__global__ __launch_bounds__(256) void xcalc_k(const float* __restrict__ psum,
                                               float* __restrict__ x) {
    int k = blockIdx.x * 256 + threadIdx.x;
    if (k >= PP) return;
    int col = k * SRR;
    float s = 0.f;
    for (int c2 = 0; c2 < NCHUNK; ++c2) s += psum[(size_t)c2 * CC + col];
    x[k] = s * (1.0f / (float)NROWS);
}

// ---------------- split helpers ---------------------------------------
__device__ __forceinline__ void split_bf16(float v, unsigned short& hi, unsigned short& lo) {
    __hip_bfloat16 h = __float2bfloat16(v);
    float r = v - __bfloat162float(h);
    __hip_bfloat16 l2 = __float2bfloat16(r);
    hi = *(unsigned short*)&h;
    lo = *(unsigned short*)&l2;
}

// ---------------- layer 1: h1 = relu(x*W1+b1) -> split bf16 -----------
__global__ __launch_bounds__(256) void layer1_k(const float* __restrict__ x,
                                                const float* __restrict__ W1,
                                                const float* __restrict__ b1,
                                                unsigned short* __restrict__ hh,
                                                unsigned short* __restrict__ hl) {
    int base = (blockIdx.x * 256 + threadIdx.x) * 4;
    int k = base >> 10, o = base & 1023;
    float xv = x[k];
    float4 w = *(const float4*)&W1[o];
    float4 b = *(const float4*)&b1[o];
    float v[4] = {xv * w.x + b.x, xv * w.y + b.y, xv * w.z + b.z, xv * w.w + b.w};
    ushort hi4[4], lo4[4];
    #pragma unroll
    for (int i = 0; i < 4; ++i) {
        float r = v[i] > 0.f ? v[i] : 0.f;
        split_bf16(r, hi4[i], lo4[i]);
    }
    *(ushort4*)&hh[base] = *(ushort4*)hi4;
    *(ushort4*)&hl[base] = *(ushort4*)lo4;
}

// ---------------- W2/W3 -> split bf16 ---------------------------------
__global__ __launch_bounds__(256) void wconv_k(const float* __restrict__ W2,
                                               unsigned short* __restrict__ w2h,
                                               unsigned short* __restrict__ w2l,
                                               const float* __restrict__ W3,
                                               unsigned short* __restrict__ w3h,
                                               unsigned short* __restrict__ w3l) {
    int b = blockIdx.x;
    const float* src; unsigned short *dh, *dl;
    if (b < 1024) { src = W2; dh = w2h; dl = w2l; }
    else { src = W3; dh = w3h; dl = w3l; b -= 1024; }
    int idx = b * 1024 + threadIdx.x * 4;
    float4 v = *(const float4*)&src[idx];
    float vv[4] = {v.x, v.y, v.z, v.w};
    ushort hi4[4], lo4[4];
    #pragma unroll
    for (int i = 0; i < 4; ++i) split_bf16(vv[i], hi4[i], lo4[i]);
    *(ushort4*)&dh[idx] = *(ushort4*)hi4;
    *(ushort4*)&dl[idx] = *(ushort4*)lo4;
}

// ---------------- async global->LDS, 16B/lane -------------------------
__device__ __forceinline__ void gload16(const unsigned short* g, unsigned short* lds) {
    __builtin_amdgcn_global_load_lds(
        (const __attribute__((address_space(1))) void*)g,
        (__attribute__((address_space(3))) void*)lds,
        16, 0, 0);
}

// ---------------- bf16x3 MFMA GEMM: C = relu(A @ B^T + bias) ----------
// A: M x K (hi/lo bf16 row-major), B: N x K (hi/lo). BM=128 BN=64 BK=32.
// 4 waves; wave w computes rows [w*32, w*32+32) x all 64 cols.
// LDS frag-linear: subtile (16 rows x 32 k) stored as 64 chunks of 16B,
// chunk l = (row&15) + 16*kgroup -> lane l reads its own chunk (no conflicts).
#define BM 128
#define BN 64
#define BK 32

template<int OUT_SPLIT>
__global__ __launch_bounds__(256) void gemm3x_k(
    const unsigned short* __restrict__ Ah, const unsigned short* __restrict__ Al,
    const unsigned short* __restrict__ Bh, const unsigned short* __restrict__ Bl,
    const float* __restrict__ bias,
    float* __restrict__ Cf, unsigned short* __restrict__ Ch, unsigned short* __restrict__ Cl,
    int M, int N, int K)
{
    __shared__ unsigned short lds[12288];       // 24 KB
    unsigned short* As_h = lds;                 // 8 subtiles * 512
    unsigned short* As_l = lds + 4096;
    unsigned short* Bs_h = lds + 8192;          // 4 subtiles * 512
    unsigned short* Bs_l = lds + 10240;

    int bm = blockIdx.x * BM, bn = blockIdx.y * BN;
    int t = threadIdx.x, w = t >> 6, l = t & 63;
    int lr = l & 15, lk = l >> 4;               // frag row, k-group

    // per-lane global base offsets (elements)
    size_t offA0 = (size_t)(bm + (2 * w + 0) * 16 + lr) * K + lk * 8;
    size_t offA1 = (size_t)(bm + (2 * w + 1) * 16 + lr) * K + lk * 8;
    size_t offB  = (size_t)(bn + w * 16 + lr) * K + lk * 8;
    // wave-uniform LDS dests
    unsigned short* dA0h = As_h + (2 * w + 0) * 512;
    unsigned short* dA1h = As_h + (2 * w + 1) * 512;
    unsigned short* dA0l = As_l + (2 * w + 0) * 512;
    unsigned short* dA1l = As_l + (2 * w + 1) * 512;
    unsigned short* dBh  = Bs_h + w * 512;
    unsigned short* dBl  = Bs_l + w * 512;

    f32x4 acc[2][4];
    #pragma unroll
    for (int i = 0; i < 2; ++i)
        #pragma unroll
        for (int j = 0; j < 4; ++j) acc[i][j] = (f32x4)(0.f);

    for (int k0 = 0; k0 < K; k0 += BK) {
        gload16(Ah + offA0 + k0, dA0h);
        gload16(Ah + offA1 + k0, dA1h);
        gload16(Al + offA0 + k0, dA0l);
        gload16(Al + offA1 + k0, dA1l);
        gload16(Bh + offB + k0, dBh);
        gload16(Bl + offB + k0, dBl);
        __syncthreads();

        short8 a[2][2], bf[4][2];
        #pragma unroll
        for (int mi = 0; mi < 2; ++mi) {
            a[mi][0] = *(const short8*)&As_h[(2 * w + mi) * 512 + l * 8];
            a[mi][1] = *(const short8*)&As_l[(2 * w + mi) * 512 + l * 8];
        }
        #pragma unroll
        for (int ni = 0; ni < 4; ++ni) {
            bf[ni][0] = *(const short8*)&Bs_h[ni * 512 + l * 8];
            bf[ni][1] = *(const short8*)&Bs_l[ni * 512 + l * 8];
        }
        #pragma unroll
        for (int mi = 0; mi < 2; ++mi)
            #pragma unroll
            for (int ni = 0; ni < 4; ++ni) {
                acc[mi][ni] = __builtin_amdgcn_mfma_f32_16x16x32_bf16(a[mi][0], bf[ni][0], acc[mi][ni], 0, 0, 0);
                acc[mi][ni] = __builtin_amdgcn_mfma_f32_16x16x32_bf16(a[mi][0], bf[ni][1], acc[mi][ni], 0, 0, 0);
                acc[mi][ni] = __builtin_amdgcn_mfma_f32_16x16x32_bf16(a[mi][1], bf[ni][0], acc[mi][ni], 0, 0, 0);
            }
        __syncthreads();
    }

    // epilogue: C/D layout col=l&15, row=(l>>4)*4+r
    float bv[4];
    #pragma unroll
    for (int ni = 0; ni < 4; ++ni) bv[ni] = bias[bn + ni * 16 + lr];
    #pragma unroll
    for (int mi = 0; mi < 2; ++mi)
        #pragma unroll
        for (int ni = 0; ni < 4; ++ni)
            #pragma unroll
            for (int r = 0; r < 4; ++r) {
                int row = bm + w * 32 + mi * 16 + lk * 4 + r;
                int col = bn + ni * 16 + lr;
                float v = acc[mi][ni][r] + bv[ni];
                v = v > 0.f ? v : 0.f;               // both hidden layers relu
                if (OUT_SPLIT) {
                    unsigned short hi, lo;
                    split_bf16(v, hi, lo);
                    Ch[(size_t)row * N + col] = hi;
                    Cl[(size_t)row * N + col] = lo;
                } else {
                    Cf[(size_t)row * N + col] = v;
                }
            }
}

// ---------------- layer 4: y[k] = dot(h3[k], W4) + b4 -----------------
__global__ __launch_bounds__(256) void layer4_k(const float* __restrict__ h,
                                                const float* __restrict__ W4,
                                                const float* __restrict__ b4,
                                                float* __restrict__ y) {
    int wave = threadIdx.x >> 6;
    int lane = threadIdx.x & 63;
    int row = blockIdx.x * 4 + wave;
    const float* hr = h + (size_t)row * HH;
    float s = 0.f;
    #pragma unroll
    for (int i = 0; i < HH / 64; ++i) s += hr[lane + 64 * i] * W4[lane + 64 * i];
    #pragma unroll
    for (int off = 32; off; off >>= 1) s += __shfl_down(s, off, 64);
    if (lane == 0) y[row] = s + b4[0];
}

extern "C" void kernel_launch(void* const* d_in, const int* in_sizes, int n_in,
                              void* d_out, int out_size, void* d_ws, size_t ws_size,
                              hipStream_t stream) {
    const float* X  = (const float*)d_in[0];
    const int*   p  = (const int*)d_in[1];
    const float* W1 = (const float*)d_in[2];
    const float* b1 = (const float*)d_in[3];
    const float* W2 = (const float*)d_in[4];
    const float* b2 = (const float*)d_in[5];
    const float* W3 = (const float*)d_in[6];
    const float* b3 = (const float*)d_in[7];
    const float* W4 = (const float*)d_in[8];
    const float* b4 = (const float*)d_in[9];
    float* out = (float*)d_out;

    char* ws = (char*)d_ws;
    size_t off = 0;
    float* psum = (float*)(ws + off); off += (size_t)NCHUNK * CC * 4;
    float* xbuf = (float*)(ws + off); off += 8192;
    unsigned short* h1h = (unsigned short*)(ws + off); off += (size_t)PP * HH * 2;
    unsigned short* h1l = (unsigned short*)(ws + off); off += (size_t)PP * HH * 2;
    unsigned short* h2h = (unsigned short*)(ws + off); off += (size_t)PP * HH * 2;
    unsigned short* h2l = (unsigned short*)(ws + off); off += (size_t)PP * HH * 2;
    unsigned short* w2h = (unsigned short*)(ws + off); off += (size_t)HH * HH * 2;
    unsigned short* w2l = (unsigned short*)(ws + off); off += (size_t)HH * HH * 2;
    unsigned short* w3h = (unsigned short*)(ws + off); off += (size_t)HH * HH * 2;
    unsigned short* w3l = (unsigned short*)(ws + off); off += (size_t)HH * HH * 2;
    float* h3 = (float*)(ws + off); off += (size_t)PP * HH * 4;

    colsum_k<<<dim3(CC / 256, NCHUNK), 256, 0, stream>>>(X, p, psum);
    xcalc_k<<<PP / 256, 256, 0, stream>>>(psum, xbuf);
    wconv_k<<<2048, 256, 0, stream>>>(W2, w2h, w2l, W3, w3h, w3l);
    layer1_k<<<(PP * HH / 4) / 256, 256, 0, stream>>>(xbuf, W1, b1, h1h, h1l);
    gemm3x_k<1><<<dim3(PP / BM, HH / BN), 256, 0, stream>>>(
        h1h, h1l, w2h, w2l, b2, (float*)nullptr, h2h, h2l, PP, HH, HH);
    gemm3x_k<0><<<dim3(PP / BM, HH / BN), 256, 0, stream>>>(
        h2h, h2l, w3h, w3l, b3, h3, (unsigned short*)nullptr, (unsigned short*)nullptr, PP, HH, HH);
    layer4_k<<<PP / 4, 256, 0, stream>>>(h3, W4, b4, out);
}

// Round 3
// 112.082 us; speedup vs baseline: 1.8313x; 1.3900x over previous
//
#include <hip/hip_runtime.h>
#include <hip/hip_bf16.h>

#define CC 20480      // columns of X
#define PP 2048       // P
#define NROWS 2047    // rows reduced
#define SRR 10
#define HH 1024
#define NCH 64        // row chunks (32 rows each)

typedef __attribute__((ext_vector_type(8))) short short8;
typedef __attribute__((ext_vector_type(4))) float f32x4;

// ---------------- phase 1: gather ONLY columns 10k ---------------------
// x[k] needs m[10k] = mean_i X[i*10][(10k - p[i]) mod C]. Stride-10 gather
// touches every HBM line anyway (40B stride), but 10x fewer instructions.
__global__ __launch_bounds__(256) void colsum_k(const float* __restrict__ X,
                                                const int* __restrict__ p,
                                                float* __restrict__ psum) {
    int k = blockIdx.x * 256 + threadIdx.x;     // 0..2047
    int chunk = blockIdx.y;
    int r0 = chunk * 32;
    int r1 = r0 + 32; if (r1 > NROWS) r1 = NROWS;
    float s = 0.f;
    int base = SRR * k;
    for (int i = r0; i < r1; ++i) {
        int col = base - p[i]; if (col < 0) col += CC;   // p[i] in [0,64)
        s += X[(size_t)i * (size_t)(SRR * CC) + col];
    }
    psum[chunk * PP + k] = s;
}

__global__ __launch_bounds__(256) void xcalc_k(const float* __restrict__ psum,
                                               float* __restrict__ x) {
    int k = blockIdx.x * 256 + threadIdx.x;
    float s = 0.f;
    #pragma unroll 8
    for (int c = 0; c < NCH; ++c) s += psum[c * PP + k];
    x[k] = s * (1.0f / (float)NROWS);
}

// ---------------- split helpers ---------------------------------------
__device__ __forceinline__ void split_bf16(float v, unsigned short& hi, unsigned short& lo) {
    __hip_bfloat16 h = __float2bfloat16(v);
    float r = v - __bfloat162float(h);
    __hip_bfloat16 l2 = __float2bfloat16(r);
    hi = *(unsigned short*)&h;
    lo = *(unsigned short*)&l2;
}

// ---------------- layer 1: h1 = relu(x*W1+b1) -> split bf16 -----------
__global__ __launch_bounds__(256) void layer1_k(const float* __restrict__ x,
                                                const float* __restrict__ W1,
                                                const float* __restrict__ b1,
                                                unsigned short* __restrict__ hh,
                                                unsigned short* __restrict__ hl) {
    int base = (blockIdx.x * 256 + threadIdx.x) * 4;
    int k = base >> 10, o = base & 1023;
    float xv = x[k];
    float4 w = *(const float4*)&W1[o];
    float4 b = *(const float4*)&b1[o];
    float v[4] = {xv * w.x + b.x, xv * w.y + b.y, xv * w.z + b.z, xv * w.w + b.w};
    ushort hi4[4], lo4[4];
    #pragma unroll
    for (int i = 0; i < 4; ++i) {
        float r = v[i] > 0.f ? v[i] : 0.f;
        split_bf16(r, hi4[i], lo4[i]);
    }
    *(ushort4*)&hh[base] = *(ushort4*)hi4;
    *(ushort4*)&hl[base] = *(ushort4*)lo4;
}

// ---------------- W2/W3 -> split bf16 ---------------------------------
__global__ __launch_bounds__(256) void wconv_k(const float* __restrict__ W2,
                                               unsigned short* __restrict__ w2h,
                                               unsigned short* __restrict__ w2l,
                                               const float* __restrict__ W3,
                                               unsigned short* __restrict__ w3h,
                                               unsigned short* __restrict__ w3l) {
    int b = blockIdx.x;
    const float* src; unsigned short *dh, *dl;
    if (b < 1024) { src = W2; dh = w2h; dl = w2l; }
    else { src = W3; dh = w3h; dl = w3l; b -= 1024; }
    int idx = b * 1024 + threadIdx.x * 4;
    float4 v = *(const float4*)&src[idx];
    float vv[4] = {v.x, v.y, v.z, v.w};
    ushort hi4[4], lo4[4];
    #pragma unroll
    for (int i = 0; i < 4; ++i) split_bf16(vv[i], hi4[i], lo4[i]);
    *(ushort4*)&dh[idx] = *(ushort4*)hi4;
    *(ushort4*)&dl[idx] = *(ushort4*)lo4;
}

// ---------------- async global->LDS, 16B/lane -------------------------
__device__ __forceinline__ void gload16(const unsigned short* g, unsigned short* lds) {
    __builtin_amdgcn_global_load_lds(
        (const __attribute__((address_space(1))) void*)g,
        (__attribute__((address_space(3))) void*)lds,
        16, 0, 0);
}

// ---------------- bf16x3 MFMA GEMM, 2-phase double-buffered ------------
// C = relu(A @ B^T + bias). A: M x K (hi/lo bf16), B: N x K (hi/lo).
// BM=128 BN=64 BK=32, 4 waves; wave w owns rows [w*32, w*32+32).
// Pipeline (T3-minimum): STAGE(next) -> ds_read+MFMA(cur) -> syncthreads.
#define BM 128
#define BN 64
#define BK 32
#define LDSH 12288      // elements per buffer (24 KB)

template<int OUT_SPLIT>
__global__ __launch_bounds__(256, 1) void gemm3x_k(
    const unsigned short* __restrict__ Ah, const unsigned short* __restrict__ Al,
    const unsigned short* __restrict__ Bh, const unsigned short* __restrict__ Bl,
    const float* __restrict__ bias,
    float* __restrict__ Cf, unsigned short* __restrict__ Ch, unsigned short* __restrict__ Cl,
    int M, int N, int K)
{
    __shared__ unsigned short lds[2][LDSH];     // 48 KB total
    // buffer layout (elements): A_hi [0,4096) 8 subtiles; A_lo [4096,8192);
    //                           B_hi [8192,10240) 4 subtiles; B_lo [10240,12288)
    int bm = blockIdx.x * BM, bn = blockIdx.y * BN;
    int t = threadIdx.x, w = t >> 6, l = t & 63;
    int lr = l & 15, lk = l >> 4;

    // per-lane global element offsets (k0 added at stage time)
    size_t offA0 = (size_t)(bm + (2 * w + 0) * 16 + lr) * K + lk * 8;
    size_t offA1 = (size_t)(bm + (2 * w + 1) * 16 + lr) * K + lk * 8;
    size_t offB  = (size_t)(bn + w * 16 + lr) * K + lk * 8;

    f32x4 acc[2][4];
    #pragma unroll
    for (int i = 0; i < 2; ++i)
        #pragma unroll
        for (int j = 0; j < 4; ++j) acc[i][j] = (f32x4)(0.f);

#define STAGE(buf, k0)                                              \
    do {                                                            \
        unsigned short* L = lds[buf];                               \
        gload16(Ah + offA0 + (k0), L + (2 * w + 0) * 512);          \
        gload16(Ah + offA1 + (k0), L + (2 * w + 1) * 512);          \
        gload16(Al + offA0 + (k0), L + 4096 + (2 * w + 0) * 512);   \
        gload16(Al + offA1 + (k0), L + 4096 + (2 * w + 1) * 512);   \
        gload16(Bh + offB + (k0),  L + 8192 + w * 512);             \
        gload16(Bl + offB + (k0),  L + 10240 + w * 512);            \
    } while (0)

    STAGE(0, 0);
    __syncthreads();                      // drains prologue loads

    int nt = K / BK;                      // 32 steps
    for (int tt = 0; tt < nt; ++tt) {
        int cur = tt & 1;
        if (tt + 1 < nt) STAGE(cur ^ 1, (tt + 1) * BK);   // prefetch next
        unsigned short* L = lds[cur];
        short8 a[2][2], bf[4][2];
        #pragma unroll
        for (int mi = 0; mi < 2; ++mi) {
            a[mi][0] = *(const short8*)&L[(2 * w + mi) * 512 + l * 8];
            a[mi][1] = *(const short8*)&L[4096 + (2 * w + mi) * 512 + l * 8];
        }
        #pragma unroll
        for (int ni = 0; ni < 4; ++ni) {
            bf[ni][0] = *(const short8*)&L[8192 + ni * 512 + l * 8];
            bf[ni][1] = *(const short8*)&L[10240 + ni * 512 + l * 8];
        }
        #pragma unroll
        for (int mi = 0; mi < 2; ++mi)
            #pragma unroll
            for (int ni = 0; ni < 4; ++ni) {
                acc[mi][ni] = __builtin_amdgcn_mfma_f32_16x16x32_bf16(a[mi][0], bf[ni][0], acc[mi][ni], 0, 0, 0);
                acc[mi][ni] = __builtin_amdgcn_mfma_f32_16x16x32_bf16(a[mi][0], bf[ni][1], acc[mi][ni], 0, 0, 0);
                acc[mi][ni] = __builtin_amdgcn_mfma_f32_16x16x32_bf16(a[mi][1], bf[ni][0], acc[mi][ni], 0, 0, 0);
            }
        __syncthreads();                  // all waves done reading cur; next buf landed
    }
#undef STAGE

    // epilogue: C/D layout col=l&15, row=(l>>4)*4+r
    float bv[4];
    #pragma unroll
    for (int ni = 0; ni < 4; ++ni) bv[ni] = bias[bn + ni * 16 + lr];
    #pragma unroll
    for (int mi = 0; mi < 2; ++mi)
        #pragma unroll
        for (int ni = 0; ni < 4; ++ni)
            #pragma unroll
            for (int r = 0; r < 4; ++r) {
                int row = bm + w * 32 + mi * 16 + lk * 4 + r;
                int col = bn + ni * 16 + lr;
                float v = acc[mi][ni][r] + bv[ni];
                v = v > 0.f ? v : 0.f;
                if (OUT_SPLIT) {
                    unsigned short hi, lo;
                    split_bf16(v, hi, lo);
                    Ch[(size_t)row * N + col] = hi;
                    Cl[(size_t)row * N + col] = lo;
                } else {
                    Cf[(size_t)row * N + col] = v;
                }
            }
}

// ---------------- layer 4: y[k] = dot(h3[k], W4) + b4 -----------------
__global__ __launch_bounds__(256) void layer4_k(const float* __restrict__ h,
                                                const float* __restrict__ W4,
                                                const float* __restrict__ b4,
                                                float* __restrict__ y) {
    int wave = threadIdx.x >> 6;
    int lane = threadIdx.x & 63;
    int row = blockIdx.x * 4 + wave;
    const float* hr = h + (size_t)row * HH;
    float s = 0.f;
    #pragma unroll
    for (int i = 0; i < HH / 64; ++i) s += hr[lane + 64 * i] * W4[lane + 64 * i];
    #pragma unroll
    for (int off = 32; off; off >>= 1) s += __shfl_down(s, off, 64);
    if (lane == 0) y[row] = s + b4[0];
}

extern "C" void kernel_launch(void* const* d_in, const int* in_sizes, int n_in,
                              void* d_out, int out_size, void* d_ws, size_t ws_size,
                              hipStream_t stream) {
    const float* X  = (const float*)d_in[0];
    const int*   p  = (const int*)d_in[1];
    const float* W1 = (const float*)d_in[2];
    const float* b1 = (const float*)d_in[3];
    const float* W2 = (const float*)d_in[4];
    const float* b2 = (const float*)d_in[5];
    const float* W3 = (const float*)d_in[6];
    const float* b3 = (const float*)d_in[7];
    const float* W4 = (const float*)d_in[8];
    const float* b4 = (const float*)d_in[9];
    float* out = (float*)d_out;

    char* ws = (char*)d_ws;
    size_t off = 0;
    float* psum = (float*)(ws + off); off += (size_t)NCH * PP * 4;
    float* xbuf = (float*)(ws + off); off += 8192;
    unsigned short* h1h = (unsigned short*)(ws + off); off += (size_t)PP * HH * 2;
    unsigned short* h1l = (unsigned short*)(ws + off); off += (size_t)PP * HH * 2;
    unsigned short* h2h = (unsigned short*)(ws + off); off += (size_t)PP * HH * 2;
    unsigned short* h2l = (unsigned short*)(ws + off); off += (size_t)PP * HH * 2;
    unsigned short* w2h = (unsigned short*)(ws + off); off += (size_t)HH * HH * 2;
    unsigned short* w2l = (unsigned short*)(ws + off); off += (size_t)HH * HH * 2;
    unsigned short* w3h = (unsigned short*)(ws + off); off += (size_t)HH * HH * 2;
    unsigned short* w3l = (unsigned short*)(ws + off); off += (size_t)HH * HH * 2;
    float* h3 = (float*)(ws + off); off += (size_t)PP * HH * 4;

    colsum_k<<<dim3(PP / 256, NCH), 256, 0, stream>>>(X, p, psum);
    xcalc_k<<<PP / 256, 256, 0, stream>>>(psum, xbuf);
    wconv_k<<<2048, 256, 0, stream>>>(W2, w2h, w2l, W3, w3h, w3l);
    layer1_k<<<(PP * HH / 4) / 256, 256, 0, stream>>>(xbuf, W1, b1, h1h, h1l);
    gemm3x_k<1><<<dim3(PP / BM, HH / BN), 256, 0, stream>>>(
        h1h, h1l, w2h, w2l, b2, (float*)nullptr, h2h, h2l, PP, HH, HH);
    gemm3x_k<0><<<dim3(PP / BM, HH / BN), 256, 0, stream>>>(
        h2h, h2l, w3h, w3l, b3, h3, (unsigned short*)nullptr, (unsigned short*)nullptr, PP, HH, HH);
    layer4_k<<<PP / 4, 256, 0, stream>>>(h3, W4, b4, out);
}

// Round 4
// 110.229 us; speedup vs baseline: 1.8621x; 1.0168x over previous
//
#include <hip/hip_runtime.h>
#include <hip/hip_bf16.h>

#define CC 20480      // columns of X
#define PP 2048       // P
#define NROWS 2047    // rows reduced
#define SRR 10
#define HH 1024
#define NCH 64        // row chunks (32 rows each)

typedef __attribute__((ext_vector_type(8))) short short8;
typedef __attribute__((ext_vector_type(4))) float f32x4;

// ---------------- phase 1: gather ONLY columns 10k ---------------------
__global__ __launch_bounds__(256) void colsum_k(const float* __restrict__ X,
                                                const int* __restrict__ p,
                                                float* __restrict__ psum) {
    int k = blockIdx.x * 256 + threadIdx.x;     // 0..2047
    int chunk = blockIdx.y;
    int r0 = chunk * 32;
    int r1 = r0 + 32; if (r1 > NROWS) r1 = NROWS;
    float s = 0.f;
    int base = SRR * k;
    for (int i = r0; i < r1; ++i) {
        int col = base - p[i]; if (col < 0) col += CC;   // p[i] in [0,64)
        s += X[(size_t)i * (size_t)(SRR * CC) + col];
    }
    psum[chunk * PP + k] = s;
}

__global__ __launch_bounds__(256) void xcalc_k(const float* __restrict__ psum,
                                               float* __restrict__ x) {
    int k = blockIdx.x * 256 + threadIdx.x;
    float s = 0.f;
    #pragma unroll 8
    for (int c = 0; c < NCH; ++c) s += psum[c * PP + k];
    x[k] = s * (1.0f / (float)NROWS);
}

// ---------------- split helpers ---------------------------------------
__device__ __forceinline__ void split_bf16(float v, unsigned short& hi, unsigned short& lo) {
    __hip_bfloat16 h = __float2bfloat16(v);
    float r = v - __bfloat162float(h);
    __hip_bfloat16 l2 = __float2bfloat16(r);
    hi = *(unsigned short*)&h;
    lo = *(unsigned short*)&l2;
}

// ---------------- layer 1: h1 = relu(x*W1+b1) -> split bf16 -----------
__global__ __launch_bounds__(256) void layer1_k(const float* __restrict__ x,
                                                const float* __restrict__ W1,
                                                const float* __restrict__ b1,
                                                unsigned short* __restrict__ hh,
                                                unsigned short* __restrict__ hl) {
    int base = (blockIdx.x * 256 + threadIdx.x) * 4;
    int k = base >> 10, o = base & 1023;
    float xv = x[k];
    float4 w = *(const float4*)&W1[o];
    float4 b = *(const float4*)&b1[o];
    float v[4] = {xv * w.x + b.x, xv * w.y + b.y, xv * w.z + b.z, xv * w.w + b.w};
    ushort hi4[4], lo4[4];
    #pragma unroll
    for (int i = 0; i < 4; ++i) {
        float r = v[i] > 0.f ? v[i] : 0.f;
        split_bf16(r, hi4[i], lo4[i]);
    }
    *(ushort4*)&hh[base] = *(ushort4*)hi4;
    *(ushort4*)&hl[base] = *(ushort4*)lo4;
}

// ---------------- W2/W3 -> split bf16 ---------------------------------
__global__ __launch_bounds__(256) void wconv_k(const float* __restrict__ W2,
                                               unsigned short* __restrict__ w2h,
                                               unsigned short* __restrict__ w2l,
                                               const float* __restrict__ W3,
                                               unsigned short* __restrict__ w3h,
                                               unsigned short* __restrict__ w3l) {
    int b = blockIdx.x;
    const float* src; unsigned short *dh, *dl;
    if (b < 1024) { src = W2; dh = w2h; dl = w2l; }
    else { src = W3; dh = w3h; dl = w3l; b -= 1024; }
    int idx = b * 1024 + threadIdx.x * 4;
    float4 v = *(const float4*)&src[idx];
    float vv[4] = {v.x, v.y, v.z, v.w};
    ushort hi4[4], lo4[4];
    #pragma unroll
    for (int i = 0; i < 4; ++i) split_bf16(vv[i], hi4[i], lo4[i]);
    *(ushort4*)&dh[idx] = *(ushort4*)hi4;
    *(ushort4*)&dl[idx] = *(ushort4*)lo4;
}

// ---------------- async global->LDS, 16B/lane -------------------------
__device__ __forceinline__ void gload16(const unsigned short* g, unsigned short* lds) {
    __builtin_amdgcn_global_load_lds(
        (const __attribute__((address_space(1))) void*)g,
        (__attribute__((address_space(3))) void*)lds,
        16, 0, 0);
}

// ---------------- bf16x3 MFMA GEMM, 2 blocks/CU + XCD locality ---------
// C = relu(A @ B^T + bias). A: M x K (hi/lo bf16), B: N x K (hi/lo).
// BM=BN=64, BK=64, 4 waves; wave (wr,wc) owns 32x32 of the output.
// Grid = 512 linear blocks, XCD-chunked (lin%8 -> chunk of 64 virtual ids,
// N-tile fastest) so each XCD's L2 holds the whole weight matrix (4 MB)
// plus its 1 MB A-slice.
#define BM 64
#define BN 64
#define BK 64
#define NBY 16        // N / BN
#define BUFE 16384    // elements per LDS buffer (32 KB)

template<int OUT_SPLIT>
__global__ __launch_bounds__(256, 2) void gemm3x_k(
    const unsigned short* __restrict__ Ah, const unsigned short* __restrict__ Al,
    const unsigned short* __restrict__ Bh, const unsigned short* __restrict__ Bl,
    const float* __restrict__ bias,
    float* __restrict__ Cf, unsigned short* __restrict__ Ch, unsigned short* __restrict__ Cl,
    int M, int N, int K)
{
    __shared__ unsigned short lds[2][BUFE];   // 64 KB total -> 2 blocks/CU
    // per buffer: A_hi [0,4096)  = 4 row-groups x (2 slices x 512)
    //             A_lo [4096,8192), B_hi [8192,12288), B_lo [12288,16384)
    int lin = blockIdx.x;
    int v = (lin & 7) * (gridDim.x >> 3) + (lin >> 3);   // bijective, grid%8==0
    int bx = v >> 4, by = v & (NBY - 1);                 // N-tile fastest
    int bm = bx * BM, bn = by * BN;
    int t = threadIdx.x, w = t >> 6, l = t & 63;
    int lr = l & 15, lk = l >> 4;
    int wr = w >> 1, wc = w & 1;

    // wave w stages row-group g=w of A and B (both halves, both k-slices)
    size_t offA = (size_t)(bm + w * 16 + lr) * K + lk * 8;
    size_t offB = (size_t)(bn + w * 16 + lr) * K + lk * 8;

#define STAGE(buf, k0)                                                  \
    do {                                                                \
        unsigned short* L = lds[buf];                                   \
        gload16(Ah + offA + (k0),      L + w * 1024);                   \
        gload16(Ah + offA + (k0) + 32, L + w * 1024 + 512);             \
        gload16(Al + offA + (k0),      L + 4096 + w * 1024);            \
        gload16(Al + offA + (k0) + 32, L + 4096 + w * 1024 + 512);      \
        gload16(Bh + offB + (k0),      L + 8192 + w * 1024);            \
        gload16(Bh + offB + (k0) + 32, L + 8192 + w * 1024 + 512);      \
        gload16(Bl + offB + (k0),      L + 12288 + w * 1024);           \
        gload16(Bl + offB + (k0) + 32, L + 12288 + w * 1024 + 512);     \
    } while (0)

    f32x4 acc[2][2];
    #pragma unroll
    for (int i = 0; i < 2; ++i)
        #pragma unroll
        for (int j = 0; j < 2; ++j) acc[i][j] = (f32x4)(0.f);

    STAGE(0, 0);
    __syncthreads();

    int nt = K / BK;                       // 16 steps
    for (int tt = 0; tt < nt; ++tt) {
        int cur = tt & 1;
        if (tt + 1 < nt) STAGE(cur ^ 1, (tt + 1) * BK);
        unsigned short* L = lds[cur];
        #pragma unroll
        for (int s = 0; s < 2; ++s) {      // two k=32 slices
            short8 ah2[2], al2[2], bh2[2], bl2[2];
            #pragma unroll
            for (int mi = 0; mi < 2; ++mi) {
                ah2[mi] = *(const short8*)&L[(wr * 2 + mi) * 1024 + s * 512 + l * 8];
                al2[mi] = *(const short8*)&L[4096 + (wr * 2 + mi) * 1024 + s * 512 + l * 8];
            }
            #pragma unroll
            for (int ni = 0; ni < 2; ++ni) {
                bh2[ni] = *(const short8*)&L[8192 + (wc * 2 + ni) * 1024 + s * 512 + l * 8];
                bl2[ni] = *(const short8*)&L[12288 + (wc * 2 + ni) * 1024 + s * 512 + l * 8];
            }
            #pragma unroll
            for (int mi = 0; mi < 2; ++mi)
                #pragma unroll
                for (int ni = 0; ni < 2; ++ni) {
                    acc[mi][ni] = __builtin_amdgcn_mfma_f32_16x16x32_bf16(ah2[mi], bh2[ni], acc[mi][ni], 0, 0, 0);
                    acc[mi][ni] = __builtin_amdgcn_mfma_f32_16x16x32_bf16(ah2[mi], bl2[ni], acc[mi][ni], 0, 0, 0);
                    acc[mi][ni] = __builtin_amdgcn_mfma_f32_16x16x32_bf16(al2[mi], bh2[ni], acc[mi][ni], 0, 0, 0);
                }
        }
        __syncthreads();
    }
#undef STAGE

    // epilogue: C/D layout col=l&15, row=(l>>4)*4+r
    float bv[2];
    #pragma unroll
    for (int ni = 0; ni < 2; ++ni) bv[ni] = bias[bn + wc * 32 + ni * 16 + lr];
    #pragma unroll
    for (int mi = 0; mi < 2; ++mi)
        #pragma unroll
        for (int ni = 0; ni < 2; ++ni)
            #pragma unroll
            for (int r = 0; r < 4; ++r) {
                int row = bm + wr * 32 + mi * 16 + lk * 4 + r;
                int col = bn + wc * 32 + ni * 16 + lr;
                float vv = acc[mi][ni][r] + bv[ni];
                vv = vv > 0.f ? vv : 0.f;
                if (OUT_SPLIT) {
                    unsigned short hi, lo;
                    split_bf16(vv, hi, lo);
                    Ch[(size_t)row * N + col] = hi;
                    Cl[(size_t)row * N + col] = lo;
                } else {
                    Cf[(size_t)row * N + col] = vv;
                }
            }
}

// ---------------- layer 4: y[k] = dot(h3[k], W4) + b4 -----------------
__global__ __launch_bounds__(256) void layer4_k(const float* __restrict__ h,
                                                const float* __restrict__ W4,
                                                const float* __restrict__ b4,
                                                float* __restrict__ y) {
    int wave = threadIdx.x >> 6;
    int lane = threadIdx.x & 63;
    int row = blockIdx.x * 4 + wave;
    const float* hr = h + (size_t)row * HH;
    float s = 0.f;
    #pragma unroll
    for (int i = 0; i < HH / 64; ++i) s += hr[lane + 64 * i] * W4[lane + 64 * i];
    #pragma unroll
    for (int off = 32; off; off >>= 1) s += __shfl_down(s, off, 64);
    if (lane == 0) y[row] = s + b4[0];
}

extern "C" void kernel_launch(void* const* d_in, const int* in_sizes, int n_in,
                              void* d_out, int out_size, void* d_ws, size_t ws_size,
                              hipStream_t stream) {
    const float* X  = (const float*)d_in[0];
    const int*   p  = (const int*)d_in[1];
    const float* W1 = (const float*)d_in[2];
    const float* b1 = (const float*)d_in[3];
    const float* W2 = (const float*)d_in[4];
    const float* b2 = (const float*)d_in[5];
    const float* W3 = (const float*)d_in[6];
    const float* b3 = (const float*)d_in[7];
    const float* W4 = (const float*)d_in[8];
    const float* b4 = (const float*)d_in[9];
    float* out = (float*)d_out;

    char* ws = (char*)d_ws;
    size_t off = 0;
    float* psum = (float*)(ws + off); off += (size_t)NCH * PP * 4;
    float* xbuf = (float*)(ws + off); off += 8192;
    unsigned short* h1h = (unsigned short*)(ws + off); off += (size_t)PP * HH * 2;
    unsigned short* h1l = (unsigned short*)(ws + off); off += (size_t)PP * HH * 2;
    unsigned short* h2h = (unsigned short*)(ws + off); off += (size_t)PP * HH * 2;
    unsigned short* h2l = (unsigned short*)(ws + off); off += (size_t)PP * HH * 2;
    unsigned short* w2h = (unsigned short*)(ws + off); off += (size_t)HH * HH * 2;
    unsigned short* w2l = (unsigned short*)(ws + off); off += (size_t)HH * HH * 2;
    unsigned short* w3h = (unsigned short*)(ws + off); off += (size_t)HH * HH * 2;
    unsigned short* w3l = (unsigned short*)(ws + off); off += (size_t)HH * HH * 2;
    float* h3 = (float*)(ws + off); off += (size_t)PP * HH * 4;

    colsum_k<<<dim3(PP / 256, NCH), 256, 0, stream>>>(X, p, psum);
    xcalc_k<<<PP / 256, 256, 0, stream>>>(psum, xbuf);
    wconv_k<<<2048, 256, 0, stream>>>(W2, w2h, w2l, W3, w3h, w3l);
    layer1_k<<<(PP * HH / 4) / 256, 256, 0, stream>>>(xbuf, W1, b1, h1h, h1l);
    gemm3x_k<1><<<(PP / BM) * (HH / BN), 256, 0, stream>>>(
        h1h, h1l, w2h, w2l, b2, (float*)nullptr, h2h, h2l, PP, HH, HH);
    gemm3x_k<0><<<(PP / BM) * (HH / BN), 256, 0, stream>>>(
        h2h, h2l, w3h, w3l, b3, h3, (unsigned short*)nullptr, (unsigned short*)nullptr, PP, HH, HH);
    layer4_k<<<PP / 4, 256, 0, stream>>>(h3, W4, b4, out);
}

// Round 5
// 106.535 us; speedup vs baseline: 1.9266x; 1.0347x over previous
//
#include <hip/hip_runtime.h>
#include <hip/hip_bf16.h>

#define CC 20480      // columns of X
#define PP 2048       // P
#define NROWS 2047    // rows reduced
#define SRR 10
#define HH 1024
#define NCH 64        // row chunks (32 rows each)

typedef __attribute__((ext_vector_type(8))) short short8;
typedef __attribute__((ext_vector_type(4))) float f32x4;

// ---------------- phase 1: gather ONLY columns 10k ---------------------
__global__ __launch_bounds__(256) void colsum_k(const float* __restrict__ X,
                                                const int* __restrict__ p,
                                                float* __restrict__ psum) {
    int k = blockIdx.x * 256 + threadIdx.x;     // 0..2047
    int chunk = blockIdx.y;
    int r0 = chunk * 32;
    int r1 = r0 + 32; if (r1 > NROWS) r1 = NROWS;
    float s = 0.f;
    int base = SRR * k;
    for (int i = r0; i < r1; ++i) {
        int col = base - p[i]; if (col < 0) col += CC;   // p[i] in [0,64)
        s += X[(size_t)i * (size_t)(SRR * CC) + col];
    }
    psum[chunk * PP + k] = s;
}

// ---------------- split helper ----------------------------------------
__device__ __forceinline__ void split_bf16(float v, unsigned short& hi, unsigned short& lo) {
    __hip_bfloat16 h = __float2bfloat16(v);
    float r = v - __bfloat162float(h);
    __hip_bfloat16 l2 = __float2bfloat16(r);
    hi = *(unsigned short*)&h;
    lo = *(unsigned short*)&l2;
}

// ---------------- fused prep: xcalc + layer1 + wconv -------------------
// blocks 0..31   : compute x for 64 rows, then h1 = relu(x*W1+b1) split
// blocks 32..543 : convert W2 (bb<256) / W3 (bb>=256) to split bf16
__global__ __launch_bounds__(256) void prep_k(const float* __restrict__ psum,
                                              const float* __restrict__ W1,
                                              const float* __restrict__ b1,
                                              unsigned short* __restrict__ h1h,
                                              unsigned short* __restrict__ h1l,
                                              const float* __restrict__ W2,
                                              unsigned short* __restrict__ w2h,
                                              unsigned short* __restrict__ w2l,
                                              const float* __restrict__ W3,
                                              unsigned short* __restrict__ w3h,
                                              unsigned short* __restrict__ w3l) {
    int b = blockIdx.x, t = threadIdx.x;
    if (b >= 32) {
        int bb = b - 32;
        const float* src; unsigned short *dh, *dl;
        if (bb < 256) { src = W2; dh = w2h; dl = w2l; }
        else { src = W3; dh = w3h; dl = w3l; bb -= 256; }
        int idx = bb * 4096 + t * 16;
        #pragma unroll
        for (int q = 0; q < 4; ++q) {
            float4 v = *(const float4*)&src[idx + q * 4];
            float vv[4] = {v.x, v.y, v.z, v.w};
            ushort hi4[4], lo4[4];
            #pragma unroll
            for (int i = 0; i < 4; ++i) split_bf16(vv[i], hi4[i], lo4[i]);
            *(ushort4*)&dh[idx + q * 4] = *(ushort4*)hi4;
            *(ushort4*)&dl[idx + q * 4] = *(ushort4*)lo4;
        }
        return;
    }
    // ---- phase A: x[k] for k in [b*64, b*64+64) ----
    __shared__ float xv[64];
    int kl = t >> 2;                  // 0..63
    int k = b * 64 + kl;
    int c0 = (t & 3) * 16;
    float s = 0.f;
    #pragma unroll
    for (int j = 0; j < 16; ++j) s += psum[(c0 + j) * PP + k];
    s += __shfl_xor(s, 1, 64);
    s += __shfl_xor(s, 2, 64);
    if ((t & 3) == 0) xv[kl] = s * (1.0f / (float)NROWS);
    __syncthreads();
    // ---- phase B: h1 rows ----
    int o0 = (t & 63) * 16;
    int r0 = (t >> 6) * 16;
    float w[16], bb2[16];
    #pragma unroll
    for (int q = 0; q < 4; ++q) {
        float4 wv = *(const float4*)&W1[o0 + q * 4];
        float4 bv = *(const float4*)&b1[o0 + q * 4];
        w[q*4+0] = wv.x; w[q*4+1] = wv.y; w[q*4+2] = wv.z; w[q*4+3] = wv.w;
        bb2[q*4+0] = bv.x; bb2[q*4+1] = bv.y; bb2[q*4+2] = bv.z; bb2[q*4+3] = bv.w;
    }
    for (int r = r0; r < r0 + 16; ++r) {
        float x = xv[r];
        ushort hi16[16], lo16[16];
        #pragma unroll
        for (int i = 0; i < 16; ++i) {
            float v = x * w[i] + bb2[i];
            v = v > 0.f ? v : 0.f;
            split_bf16(v, hi16[i], lo16[i]);
        }
        size_t base = (size_t)(b * 64 + r) * HH + o0;
        *(short8*)&h1h[base] = *(short8*)hi16;
        *(short8*)&h1h[base + 8] = *(short8*)&hi16[8];
        *(short8*)&h1l[base] = *(short8*)lo16;
        *(short8*)&h1l[base + 8] = *(short8*)&lo16[8];
    }
}

// ---------------- async global->LDS, 16B/lane -------------------------
__device__ __forceinline__ void gload16(const unsigned short* g, unsigned short* lds) {
    __builtin_amdgcn_global_load_lds(
        (const __attribute__((address_space(1))) void*)g,
        (__attribute__((address_space(3))) void*)lds,
        16, 0, 0);
}

// ---------------- bf16x3 MFMA GEMM -------------------------------------
// C = relu(A @ B^T + bias). BM=BN=64, BK=64, 4 waves, wave (wr,wc) owns
// 32x32 output. OUT=1: write split hi/lo. OUT=2: fused W4 partial dots
// (no C written; partial[row*32 + by*2 + wc] = sum over wave's 32 cols).
#define BM 64
#define BN 64
#define BK 64
#define NBY 16        // N / BN
#define BUFE 16384    // elements per LDS buffer (32 KB)

template<int OUT>
__global__ __launch_bounds__(256, 2) void gemm3x_k(
    const unsigned short* __restrict__ Ah, const unsigned short* __restrict__ Al,
    const unsigned short* __restrict__ Bh, const unsigned short* __restrict__ Bl,
    const float* __restrict__ bias,
    unsigned short* __restrict__ Ch, unsigned short* __restrict__ Cl,
    const float* __restrict__ W4, float* __restrict__ partial,
    int M, int N, int K)
{
    __shared__ unsigned short lds[2][BUFE];   // 64 KB total -> 2 blocks/CU
    int lin = blockIdx.x;
    int v = (lin & 7) * (gridDim.x >> 3) + (lin >> 3);   // bijective, grid%8==0
    int bx = v >> 4, by = v & (NBY - 1);                 // N-tile fastest
    int bm = bx * BM, bn = by * BN;
    int t = threadIdx.x, w = t >> 6, l = t & 63;
    int lr = l & 15, lk = l >> 4;
    int wr = w >> 1, wc = w & 1;

    size_t offA = (size_t)(bm + w * 16 + lr) * K + lk * 8;
    size_t offB = (size_t)(bn + w * 16 + lr) * K + lk * 8;

#define STAGE(buf, k0)                                                  \
    do {                                                                \
        unsigned short* L = lds[buf];                                   \
        gload16(Ah + offA + (k0),      L + w * 1024);                   \
        gload16(Ah + offA + (k0) + 32, L + w * 1024 + 512);             \
        gload16(Al + offA + (k0),      L + 4096 + w * 1024);            \
        gload16(Al + offA + (k0) + 32, L + 4096 + w * 1024 + 512);      \
        gload16(Bh + offB + (k0),      L + 8192 + w * 1024);            \
        gload16(Bh + offB + (k0) + 32, L + 8192 + w * 1024 + 512);      \
        gload16(Bl + offB + (k0),      L + 12288 + w * 1024);           \
        gload16(Bl + offB + (k0) + 32, L + 12288 + w * 1024 + 512);     \
    } while (0)

    f32x4 acc[2][2];
    #pragma unroll
    for (int i = 0; i < 2; ++i)
        #pragma unroll
        for (int j = 0; j < 2; ++j) acc[i][j] = (f32x4)(0.f);

    STAGE(0, 0);
    __syncthreads();

    int nt = K / BK;
    for (int tt = 0; tt < nt; ++tt) {
        int cur = tt & 1;
        if (tt + 1 < nt) STAGE(cur ^ 1, (tt + 1) * BK);
        unsigned short* L = lds[cur];
        #pragma unroll
        for (int s = 0; s < 2; ++s) {
            short8 ah2[2], al2[2], bh2[2], bl2[2];
            #pragma unroll
            for (int mi = 0; mi < 2; ++mi) {
                ah2[mi] = *(const short8*)&L[(wr * 2 + mi) * 1024 + s * 512 + l * 8];
                al2[mi] = *(const short8*)&L[4096 + (wr * 2 + mi) * 1024 + s * 512 + l * 8];
            }
            #pragma unroll
            for (int ni = 0; ni < 2; ++ni) {
                bh2[ni] = *(const short8*)&L[8192 + (wc * 2 + ni) * 1024 + s * 512 + l * 8];
                bl2[ni] = *(const short8*)&L[12288 + (wc * 2 + ni) * 1024 + s * 512 + l * 8];
            }
            #pragma unroll
            for (int mi = 0; mi < 2; ++mi)
                #pragma unroll
                for (int ni = 0; ni < 2; ++ni) {
                    acc[mi][ni] = __builtin_amdgcn_mfma_f32_16x16x32_bf16(ah2[mi], bh2[ni], acc[mi][ni], 0, 0, 0);
                    acc[mi][ni] = __builtin_amdgcn_mfma_f32_16x16x32_bf16(ah2[mi], bl2[ni], acc[mi][ni], 0, 0, 0);
                    acc[mi][ni] = __builtin_amdgcn_mfma_f32_16x16x32_bf16(al2[mi], bh2[ni], acc[mi][ni], 0, 0, 0);
                }
        }
        __syncthreads();
    }
#undef STAGE

    // epilogue: C/D layout col=l&15, row=(l>>4)*4+r
    float bv[2];
    #pragma unroll
    for (int ni = 0; ni < 2; ++ni) bv[ni] = bias[bn + wc * 32 + ni * 16 + lr];
    if (OUT == 1) {
        #pragma unroll
        for (int mi = 0; mi < 2; ++mi)
            #pragma unroll
            for (int ni = 0; ni < 2; ++ni)
                #pragma unroll
                for (int r = 0; r < 4; ++r) {
                    int row = bm + wr * 32 + mi * 16 + lk * 4 + r;
                    int col = bn + wc * 32 + ni * 16 + lr;
                    float vv = acc[mi][ni][r] + bv[ni];
                    vv = vv > 0.f ? vv : 0.f;
                    unsigned short hi, lo;
                    split_bf16(vv, hi, lo);
                    Ch[(size_t)row * N + col] = hi;
                    Cl[(size_t)row * N + col] = lo;
                }
    } else {
        float w4v[2];
        #pragma unroll
        for (int ni = 0; ni < 2; ++ni) w4v[ni] = W4[bn + wc * 32 + ni * 16 + lr];
        #pragma unroll
        for (int mi = 0; mi < 2; ++mi) {
            float ps[4];
            #pragma unroll
            for (int r = 0; r < 4; ++r) {
                float acc_d = 0.f;
                #pragma unroll
                for (int ni = 0; ni < 2; ++ni) {
                    float vv = acc[mi][ni][r] + bv[ni];
                    vv = vv > 0.f ? vv : 0.f;
                    acc_d += vv * w4v[ni];
                }
                ps[r] = acc_d;
            }
            // reduce across the 16 lanes (lr) of each lane-group
            #pragma unroll
            for (int r = 0; r < 4; ++r) {
                #pragma unroll
                for (int m2 = 1; m2 < 16; m2 <<= 1) ps[r] += __shfl_xor(ps[r], m2, 64);
            }
            if (lr == 0) {
                #pragma unroll
                for (int r = 0; r < 4; ++r) {
                    int row = bm + wr * 32 + mi * 16 + lk * 4 + r;
                    partial[(size_t)row * 32 + by * 2 + wc] = ps[r];
                }
            }
        }
    }
}

// ---------------- ysum: y[r] = sum(partial[r][:]) + b4 ----------------
__global__ __launch_bounds__(256) void ysum_k(const float* __restrict__ partial,
                                              const float* __restrict__ b4,
                                              float* __restrict__ y) {
    int r = blockIdx.x * 256 + threadIdx.x;
    float s = 0.f;
    #pragma unroll
    for (int q = 0; q < 8; ++q) {
        float4 v = *(const float4*)&partial[(size_t)r * 32 + q * 4];
        s += v.x + v.y + v.z + v.w;
    }
    y[r] = s + b4[0];
}

extern "C" void kernel_launch(void* const* d_in, const int* in_sizes, int n_in,
                              void* d_out, int out_size, void* d_ws, size_t ws_size,
                              hipStream_t stream) {
    const float* X  = (const float*)d_in[0];
    const int*   p  = (const int*)d_in[1];
    const float* W1 = (const float*)d_in[2];
    const float* b1 = (const float*)d_in[3];
    const float* W2 = (const float*)d_in[4];
    const float* b2 = (const float*)d_in[5];
    const float* W3 = (const float*)d_in[6];
    const float* b3 = (const float*)d_in[7];
    const float* W4 = (const float*)d_in[8];
    const float* b4 = (const float*)d_in[9];
    float* out = (float*)d_out;

    char* ws = (char*)d_ws;
    size_t off = 0;
    float* psum = (float*)(ws + off); off += (size_t)NCH * PP * 4;
    unsigned short* h1h = (unsigned short*)(ws + off); off += (size_t)PP * HH * 2;
    unsigned short* h1l = (unsigned short*)(ws + off); off += (size_t)PP * HH * 2;
    unsigned short* h2h = (unsigned short*)(ws + off); off += (size_t)PP * HH * 2;
    unsigned short* h2l = (unsigned short*)(ws + off); off += (size_t)PP * HH * 2;
    unsigned short* w2h = (unsigned short*)(ws + off); off += (size_t)HH * HH * 2;
    unsigned short* w2l = (unsigned short*)(ws + off); off += (size_t)HH * HH * 2;
    unsigned short* w3h = (unsigned short*)(ws + off); off += (size_t)HH * HH * 2;
    unsigned short* w3l = (unsigned short*)(ws + off); off += (size_t)HH * HH * 2;
    float* partial = (float*)(ws + off); off += (size_t)PP * 32 * 4;

    colsum_k<<<dim3(PP / 256, NCH), 256, 0, stream>>>(X, p, psum);
    prep_k<<<544, 256, 0, stream>>>(psum, W1, b1, h1h, h1l, W2, w2h, w2l, W3, w3h, w3l);
    gemm3x_k<1><<<(PP / BM) * (HH / BN), 256, 0, stream>>>(
        h1h, h1l, w2h, w2l, b2, h2h, h2l, (const float*)nullptr, (float*)nullptr, PP, HH, HH);
    gemm3x_k<2><<<(PP / BM) * (HH / BN), 256, 0, stream>>>(
        h2h, h2l, w3h, w3l, b3, (unsigned short*)nullptr, (unsigned short*)nullptr, W4, partial, PP, HH, HH);
    ysum_k<<<PP / 256, 256, 0, stream>>>(partial, b4, out);
}

// Round 6
// 104.689 us; speedup vs baseline: 1.9606x; 1.0176x over previous
//
#include <hip/hip_runtime.h>
#include <hip/hip_bf16.h>

#define CC 20480      // columns of X
#define PP 2048       // P
#define NROWS 2047    // rows reduced
#define SRR 10
#define HH 1024
#define NCH 64        // row chunks (32 rows each)

typedef __attribute__((ext_vector_type(8))) short short8;
typedef __attribute__((ext_vector_type(4))) float f32x4;

// ---------------- split helper ----------------------------------------
__device__ __forceinline__ void split_bf16(float v, unsigned short& hi, unsigned short& lo) {
    __hip_bfloat16 h = __float2bfloat16(v);
    float r = v - __bfloat162float(h);
    __hip_bfloat16 l2 = __float2bfloat16(r);
    hi = *(unsigned short*)&h;
    lo = *(unsigned short*)&l2;
}

// ---------------- pre: colsum (blocks 0..511) + wconv (512..1023) ------
// Grid-level fusion: wconv's VALU work rides inside colsum's HBM window.
__global__ __launch_bounds__(256) void pre_k(const float* __restrict__ X,
                                             const int* __restrict__ p,
                                             float* __restrict__ psum,
                                             const float* __restrict__ W2,
                                             unsigned short* __restrict__ w2h,
                                             unsigned short* __restrict__ w2l,
                                             const float* __restrict__ W3,
                                             unsigned short* __restrict__ w3h,
                                             unsigned short* __restrict__ w3l) {
    int b = blockIdx.x, t = threadIdx.x;
    if (b < 512) {
        int k = (b & 7) * 256 + t;              // 0..2047
        int chunk = b >> 3;                     // 0..63
        int r0 = chunk * 32;
        int r1 = r0 + 32; if (r1 > NROWS) r1 = NROWS;
        float s = 0.f;
        int base = SRR * k;
        for (int i = r0; i < r1; ++i) {
            int col = base - p[i]; if (col < 0) col += CC;   // p[i] in [0,64)
            s += X[(size_t)i * (size_t)(SRR * CC) + col];
        }
        psum[chunk * PP + k] = s;
        return;
    }
    int bb = b - 512;
    const float* src; unsigned short *dh, *dl;
    if (bb < 256) { src = W2; dh = w2h; dl = w2l; }
    else { src = W3; dh = w3h; dl = w3l; bb -= 256; }
    int idx = bb * 4096 + t * 16;
    #pragma unroll
    for (int q = 0; q < 4; ++q) {
        float4 v = *(const float4*)&src[idx + q * 4];
        float vv[4] = {v.x, v.y, v.z, v.w};
        ushort hi4[4], lo4[4];
        #pragma unroll
        for (int i = 0; i < 4; ++i) split_bf16(vv[i], hi4[i], lo4[i]);
        *(ushort4*)&dh[idx + q * 4] = *(ushort4*)hi4;
        *(ushort4*)&dl[idx + q * 4] = *(ushort4*)lo4;
    }
}

// ---------------- prep2: x (psum reduce) + layer1, 256 blocks ----------
// block b: k in [b*8, b*8+8); then h1 rows b*8..b*8+7 (8 KB writes/block).
__global__ __launch_bounds__(256) void prep2_k(const float* __restrict__ psum,
                                               const float* __restrict__ W1,
                                               const float* __restrict__ b1,
                                               unsigned short* __restrict__ h1h,
                                               unsigned short* __restrict__ h1l) {
    __shared__ float xv[8];
    int b = blockIdx.x, t = threadIdx.x;
    int kl = t >> 5;                  // 0..7
    int c = t & 31;
    int k = b * 8 + kl;
    float s = psum[c * PP + k] + psum[(c + 32) * PP + k];
    #pragma unroll
    for (int m2 = 1; m2 < 32; m2 <<= 1) s += __shfl_xor(s, m2, 64);
    if (c == 0) xv[kl] = s * (1.0f / (float)NROWS);
    __syncthreads();
    int o0 = (t & 63) * 16;
    float w[16], bb2[16];
    #pragma unroll
    for (int q = 0; q < 4; ++q) {
        float4 wv = *(const float4*)&W1[o0 + q * 4];
        float4 bv = *(const float4*)&b1[o0 + q * 4];
        w[q*4+0] = wv.x; w[q*4+1] = wv.y; w[q*4+2] = wv.z; w[q*4+3] = wv.w;
        bb2[q*4+0] = bv.x; bb2[q*4+1] = bv.y; bb2[q*4+2] = bv.z; bb2[q*4+3] = bv.w;
    }
    #pragma unroll
    for (int pass = 0; pass < 2; ++pass) {
        int r = (t >> 6) + 4 * pass;          // 0..7
        float x = xv[r];
        ushort hi16[16], lo16[16];
        #pragma unroll
        for (int i = 0; i < 16; ++i) {
            float v = x * w[i] + bb2[i];
            v = v > 0.f ? v : 0.f;
            split_bf16(v, hi16[i], lo16[i]);
        }
        size_t base = (size_t)(b * 8 + r) * HH + o0;
        *(short8*)&h1h[base] = *(short8*)hi16;
        *(short8*)&h1h[base + 8] = *(short8*)&hi16[8];
        *(short8*)&h1l[base] = *(short8*)lo16;
        *(short8*)&h1l[base + 8] = *(short8*)&lo16[8];
    }
}

// ---------------- async global->LDS, 16B/lane -------------------------
__device__ __forceinline__ void gload16(const unsigned short* g, unsigned short* lds) {
    __builtin_amdgcn_global_load_lds(
        (const __attribute__((address_space(1))) void*)g,
        (__attribute__((address_space(3))) void*)lds,
        16, 0, 0);
}

// ---------------- bf16x3 MFMA GEMM, 128x64 tile, 8 waves ---------------
// C = relu(A @ B^T + bias). Grid = 256 = 1 block/CU (full chip), 512 thr
// = 8 waves = 2 waves/SIMD. Wave (wr,wc) owns 32x32 output; 12 MFMA per
// 8 ds_read_b128 per K-step. Double-buffered 2x24 KB LDS.
#define BM 128
#define BN 64
#define BK 32
#define NBY 16        // N / BN
#define BUFE 12288    // ushorts per buffer (24 KB)

template<int OUT>
__global__ __launch_bounds__(512, 2) void gemm3x_k(
    const unsigned short* __restrict__ Ah, const unsigned short* __restrict__ Al,
    const unsigned short* __restrict__ Bh, const unsigned short* __restrict__ Bl,
    const float* __restrict__ bias,
    unsigned short* __restrict__ Ch, unsigned short* __restrict__ Cl,
    const float* __restrict__ W4, float* __restrict__ partial,
    int M, int N, int K)
{
    __shared__ unsigned short lds[2][BUFE];   // 48 KB
    // per buffer: A_hi [0,4096) 8 subtiles of 512; A_lo [4096,8192);
    //             B_hi [8192,10240) 4 subtiles; B_lo [10240,12288)
    int lin = blockIdx.x;
    int v = (lin & 7) * (gridDim.x >> 3) + (lin >> 3);   // XCD-chunked, bijective
    int bx = v >> 4, by = v & (NBY - 1);                 // N-tile fastest
    int bm = bx * BM, bn = by * BN;
    int t = threadIdx.x, w = t >> 6, l = t & 63;
    int lr = l & 15, lk = l >> 4;
    int wr = w >> 1, wc = w & 1;          // wave tile: rows wr*32, cols wc*32

    // staging: wave w loads A row-group w (hi+lo); waves 0-3 B_hi grp w,
    // waves 4-7 B_lo grp w-4.
    size_t offA = (size_t)(bm + w * 16 + lr) * K + lk * 8;
    size_t offB = (size_t)(bn + (w & 3) * 16 + lr) * K + lk * 8;

#define STAGE(buf, k0)                                                   \
    do {                                                                 \
        unsigned short* L = lds[buf];                                    \
        gload16(Ah + offA + (k0), L + w * 512);                          \
        gload16(Al + offA + (k0), L + 4096 + w * 512);                   \
        if (w < 4) gload16(Bh + offB + (k0), L + 8192 + w * 512);        \
        else       gload16(Bl + offB + (k0), L + 10240 + (w - 4) * 512); \
    } while (0)

    f32x4 acc[2][2];
    #pragma unroll
    for (int i = 0; i < 2; ++i)
        #pragma unroll
        for (int j = 0; j < 2; ++j) acc[i][j] = (f32x4)(0.f);

    STAGE(0, 0);
    __syncthreads();

    int nt = K / BK;                       // 32 steps
    for (int tt = 0; tt < nt; ++tt) {
        int cur = tt & 1;
        if (tt + 1 < nt) STAGE(cur ^ 1, (tt + 1) * BK);
        unsigned short* L = lds[cur];
        short8 ah2[2], al2[2], bh2[2], bl2[2];
        #pragma unroll
        for (int mi = 0; mi < 2; ++mi) {
            ah2[mi] = *(const short8*)&L[(wr * 2 + mi) * 512 + l * 8];
            al2[mi] = *(const short8*)&L[4096 + (wr * 2 + mi) * 512 + l * 8];
        }
        #pragma unroll
        for (int ni = 0; ni < 2; ++ni) {
            bh2[ni] = *(const short8*)&L[8192 + (wc * 2 + ni) * 512 + l * 8];
            bl2[ni] = *(const short8*)&L[10240 + (wc * 2 + ni) * 512 + l * 8];
        }
        #pragma unroll
        for (int mi = 0; mi < 2; ++mi)
            #pragma unroll
            for (int ni = 0; ni < 2; ++ni) {
                acc[mi][ni] = __builtin_amdgcn_mfma_f32_16x16x32_bf16(ah2[mi], bh2[ni], acc[mi][ni], 0, 0, 0);
                acc[mi][ni] = __builtin_amdgcn_mfma_f32_16x16x32_bf16(ah2[mi], bl2[ni], acc[mi][ni], 0, 0, 0);
                acc[mi][ni] = __builtin_amdgcn_mfma_f32_16x16x32_bf16(al2[mi], bh2[ni], acc[mi][ni], 0, 0, 0);
            }
        __syncthreads();
    }
#undef STAGE

    // epilogue: C/D layout col=l&15, row=(l>>4)*4+r
    float bv[2];
    #pragma unroll
    for (int ni = 0; ni < 2; ++ni) bv[ni] = bias[bn + wc * 32 + ni * 16 + lr];
    if (OUT == 1) {
        #pragma unroll
        for (int mi = 0; mi < 2; ++mi)
            #pragma unroll
            for (int ni = 0; ni < 2; ++ni)
                #pragma unroll
                for (int r = 0; r < 4; ++r) {
                    int row = bm + wr * 32 + mi * 16 + lk * 4 + r;
                    int col = bn + wc * 32 + ni * 16 + lr;
                    float vv = acc[mi][ni][r] + bv[ni];
                    vv = vv > 0.f ? vv : 0.f;
                    unsigned short hi, lo;
                    split_bf16(vv, hi, lo);
                    Ch[(size_t)row * N + col] = hi;
                    Cl[(size_t)row * N + col] = lo;
                }
    } else {
        float w4v[2];
        #pragma unroll
        for (int ni = 0; ni < 2; ++ni) w4v[ni] = W4[bn + wc * 32 + ni * 16 + lr];
        #pragma unroll
        for (int mi = 0; mi < 2; ++mi) {
            float ps[4];
            #pragma unroll
            for (int r = 0; r < 4; ++r) {
                float acc_d = 0.f;
                #pragma unroll
                for (int ni = 0; ni < 2; ++ni) {
                    float vv = acc[mi][ni][r] + bv[ni];
                    vv = vv > 0.f ? vv : 0.f;
                    acc_d += vv * w4v[ni];
                }
                ps[r] = acc_d;
            }
            #pragma unroll
            for (int r = 0; r < 4; ++r) {
                #pragma unroll
                for (int m2 = 1; m2 < 16; m2 <<= 1) ps[r] += __shfl_xor(ps[r], m2, 64);
            }
            if (lr == 0) {
                #pragma unroll
                for (int r = 0; r < 4; ++r) {
                    int row = bm + wr * 32 + mi * 16 + lk * 4 + r;
                    partial[(size_t)row * 32 + by * 2 + wc] = ps[r];
                }
            }
        }
    }
}

// ---------------- ysum: y[r] = sum(partial[r][:]) + b4 ----------------
__global__ __launch_bounds__(256) void ysum_k(const float* __restrict__ partial,
                                              const float* __restrict__ b4,
                                              float* __restrict__ y) {
    int r = blockIdx.x * 256 + threadIdx.x;
    float s = 0.f;
    #pragma unroll
    for (int q = 0; q < 8; ++q) {
        float4 v = *(const float4*)&partial[(size_t)r * 32 + q * 4];
        s += v.x + v.y + v.z + v.w;
    }
    y[r] = s + b4[0];
}

extern "C" void kernel_launch(void* const* d_in, const int* in_sizes, int n_in,
                              void* d_out, int out_size, void* d_ws, size_t ws_size,
                              hipStream_t stream) {
    const float* X  = (const float*)d_in[0];
    const int*   p  = (const int*)d_in[1];
    const float* W1 = (const float*)d_in[2];
    const float* b1 = (const float*)d_in[3];
    const float* W2 = (const float*)d_in[4];
    const float* b2 = (const float*)d_in[5];
    const float* W3 = (const float*)d_in[6];
    const float* b3 = (const float*)d_in[7];
    const float* W4 = (const float*)d_in[8];
    const float* b4 = (const float*)d_in[9];
    float* out = (float*)d_out;

    char* ws = (char*)d_ws;
    size_t off = 0;
    float* psum = (float*)(ws + off); off += (size_t)NCH * PP * 4;
    unsigned short* h1h = (unsigned short*)(ws + off); off += (size_t)PP * HH * 2;
    unsigned short* h1l = (unsigned short*)(ws + off); off += (size_t)PP * HH * 2;
    unsigned short* h2h = (unsigned short*)(ws + off); off += (size_t)PP * HH * 2;
    unsigned short* h2l = (unsigned short*)(ws + off); off += (size_t)PP * HH * 2;
    unsigned short* w2h = (unsigned short*)(ws + off); off += (size_t)HH * HH * 2;
    unsigned short* w2l = (unsigned short*)(ws + off); off += (size_t)HH * HH * 2;
    unsigned short* w3h = (unsigned short*)(ws + off); off += (size_t)HH * HH * 2;
    unsigned short* w3l = (unsigned short*)(ws + off); off += (size_t)HH * HH * 2;
    float* partial = (float*)(ws + off); off += (size_t)PP * 32 * 4;

    pre_k<<<1024, 256, 0, stream>>>(X, p, psum, W2, w2h, w2l, W3, w3h, w3l);
    prep2_k<<<256, 256, 0, stream>>>(psum, W1, b1, h1h, h1l);
    gemm3x_k<1><<<(PP / BM) * (HH / BN), 512, 0, stream>>>(
        h1h, h1l, w2h, w2l, b2, h2h, h2l, (const float*)nullptr, (float*)nullptr, PP, HH, HH);
    gemm3x_k<2><<<(PP / BM) * (HH / BN), 512, 0, stream>>>(
        h2h, h2l, w3h, w3l, b3, (unsigned short*)nullptr, (unsigned short*)nullptr, W4, partial, PP, HH, HH);
    ysum_k<<<PP / 256, 256, 0, stream>>>(partial, b4, out);
}